// Round 19
// baseline (1339.531 us; speedup 1.0000x reference)
//
#include <hip/hip_runtime.h>
#include <math.h>
#include <stdint.h>

#define BBOX_CLAMP 4.135166556742356f
#define SQH 0.70710678118654752f
#define SQ2 1.41421356237309515f

typedef __attribute__((ext_vector_type(8))) short s8b;
typedef __attribute__((ext_vector_type(4))) float f32x4;
typedef __attribute__((ext_vector_type(16))) float f32x16;
typedef __attribute__((ext_vector_type(4))) short s4b;

__device__ __forceinline__ unsigned okey(float f){
  unsigned u = __float_as_uint(f);
  return (u & 0x80000000u) ? ~u : (u | 0x80000000u);
}
__device__ __forceinline__ unsigned short f2bf(float f){  // RNE fp32->bf16
  unsigned u = __float_as_uint(f);
  unsigned r = (u + 0x7FFFu + ((u >> 16) & 1u)) >> 16;
  return (unsigned short)r;
}
__device__ __forceinline__ float bf2f(unsigned short h){
  return __uint_as_float(((unsigned)h) << 16);
}

// ---- one-time: split stem weights into bf16 hi/lo, MFMA-B-fragment layout ----
// whi/wlo[(((tap*8+slice)*4+g)*256 + cout)*8 + j] = split of w[cout][cin=slice*32+g*8+j][tap]
// (layout shared by the 16x16 and 32x32 B fragments: group g = 8-cin chunk)
__global__ void k_wsplit(const float* __restrict__ w,
                         unsigned short* __restrict__ whi, unsigned short* __restrict__ wlo){
  const int ck = blockIdx.x;          // cin*9 + tap
  const int cout = threadIdx.x;
  const int cin = ck / 9, tap = ck - cin*9;
  const float x = w[cout*2304 + ck];
  const unsigned short h = f2bf(x);
  const unsigned short lo2 = f2bf(x - bf2f(h));
  const int slice = cin >> 5, g = (cin >> 3) & 3, j = cin & 7;
  const size_t off = ((((size_t)tap*8 + slice)*4 + g)*256 + cout)*8 + j;
  whi[off] = h; wlo[off] = lo2;
}

// ---- fused stem conv3x3 (split-bf16 MFMA 32x32x16) + bias+relu + heads ----
// r18 plateau: 16x16x32 path pinned at MfmaUtil ~37% across every scheduling
// lever. This round changes instruction economics: 32x32x16 MFMA — half the
// MFMA instructions (48 vs 96 per wave-tap) at 2x pipe occupancy each (33.8 vs
// 19.4 cy/SIMD) and 13% faster ubench rate; latency events amortize over 2x
// pipe-busy per issue. acc = 2 Mtiles x 4 Ntiles x f32x16 = 128 AGPR; same
// staging/halo as r13; (256,2) only (min-waves>=3 always spills).
// Layouts (guide m74/m101): A row=l&31,k=(l>>5)*8+j; B col=l&31 same k;
// D col=l&31, row=(reg&3)+8*(reg>>2)+4*(l>>5).
// Per-acc chain: slice asc -> tap asc -> khalf asc -> (hihi,hilo,lohi).
__global__ __launch_bounds__(256, 2) void k_stem_mfma(
    const float* __restrict__ p3f, const float* __restrict__ p4f, const float* __restrict__ p5f,
    const unsigned short* __restrict__ whi, const unsigned short* __restrict__ wlo,
    const float* __restrict__ bstem,
    const float* __restrict__ wobj, const float* __restrict__ bobj,
    const float* __restrict__ wbox, const float* __restrict__ bbox,
    float* __restrict__ sc3, float* __restrict__ dl3,
    float* __restrict__ sc4, float* __restrict__ dl4,
    float* __restrict__ sc5, float* __restrict__ dl5)
{
  // A halo tile (2 planes x 204 x 40 u16 = 32640 B); head partials
  // (2 couthalves x 128 px x 17 f32 = 17408 B) overlay after compute.
  __shared__ __align__(16) unsigned char smem[32640];
  unsigned short* Abuf = reinterpret_cast<unsigned short*>(smem);
  float* part = reinterpret_cast<float*>(smem);

  const int tid = threadIdx.x;
  const int l = tid & 63, w = tid >> 6;
  const int li32 = l & 31, hi = l >> 5;
  const int p = w >> 1, c = w & 1;    // row pair (rows 2p,2p+1), cout half

  // ---- level decode ----
  int id = blockIdx.x;
  const float* feat; float* scores; float* deltas; int H, W, bx, by, b;
  if (id < 1024){ feat=p3f; scores=sc3; deltas=dl3; H=128; W=128;
      bx = id & 3; by = (id >> 2) & 31; b = id >> 7; }
  else if (id < 1280){ id -= 1024; feat=p4f; scores=sc4; deltas=dl4; H=64; W=64;
      bx = id & 1; by = (id >> 1) & 15; b = id >> 5; }
  else { id -= 1280; feat=p5f; scores=sc5; deltas=dl5; H=32; W=32;
      bx = 0; by = id & 7; b = id >> 3; }
  const int px0 = bx*32, py0 = by*4;
  const size_t HW = (size_t)H*W;
  const float* fb = feat + (size_t)b*256*HW;

  // ---- staging map: thread = halo pixel, iter = cin (r13-proven) ----
  const int gr = tid / 34, gc = tid - gr*34;
  const int row = py0 + gr - 1, col = px0 + gc - 1;
  const bool inb = (tid < 204) && row >= 0 && row < H && col >= 0 && col < W;
  const bool lact = (tid < 204);
  const float* gA = fb + ((size_t)(inb ? row : 0)*W + (inb ? col : 0));

  f32x16 acc[2][4];
#pragma unroll
  for (int m=0;m<2;++m)
#pragma unroll
    for (int n=0;n<4;++n)
#pragma unroll
      for (int r=0;r<16;++r) acc[m][n][r] = 0.f;

  for (int slice = 0; slice < 8; ++slice){
    __syncthreads();                      // prior slice's A reads done
    const float* gs = gA + (size_t)slice*32*HW;
#pragma unroll
    for (int ch = 0; ch < 8; ++ch){
      float x0=0.f, x1=0.f, x2=0.f, x3=0.f;
      if (inb){
        x0 = gs[(size_t)(ch*4+0)*HW];
        x1 = gs[(size_t)(ch*4+1)*HW];
        x2 = gs[(size_t)(ch*4+2)*HW];
        x3 = gs[(size_t)(ch*4+3)*HW];
      }
      if (lact){
        const unsigned short h0=f2bf(x0), h1=f2bf(x1), h2=f2bf(x2), h3=f2bf(x3);
        s4b hv; hv[0]=(short)h0; hv[1]=(short)h1; hv[2]=(short)h2; hv[3]=(short)h3;
        s4b lv; lv[0]=(short)f2bf(x0-bf2f(h0)); lv[1]=(short)f2bf(x1-bf2f(h1));
                lv[2]=(short)f2bf(x2-bf2f(h2)); lv[3]=(short)f2bf(x3-bf2f(h3));
        *reinterpret_cast<s4b*>(&Abuf[tid*40 + ch*4]) = hv;
        *reinterpret_cast<s4b*>(&Abuf[8160 + tid*40 + ch*4]) = lv;
      }
    }
    __syncthreads();

    for (int tap = 0; tap < 9; ++tap){
      const int dr = tap/3 - 1, dc = tap - (tap/3)*3 - 1;
#pragma unroll
      for (int khalf = 0; khalf < 2; ++khalf){
        // ---- A fragments: row = li32 (image col), k = khalf*16 + hi*8 + j ----
        s8b ah[2], al[2];
#pragma unroll
        for (int m = 0; m < 2; ++m){
          const int aoff = ((2*p + m + dr + 1)*34 + li32 + dc + 1)*40 + khalf*16 + hi*8;
          ah[m] = *reinterpret_cast<const s8b*>(&Abuf[aoff]);
          al[m] = *reinterpret_cast<const s8b*>(&Abuf[8160 + aoff]);
        }
        const int grp = khalf*2 + hi;     // 8-cin group within the slice
#pragma unroll
        for (int n = 0; n < 4; ++n){
          const int cout = c*128 + n*32 + li32;
          const int woff = ((((tap*8 + slice)*4 + grp)*256) + cout)*8;
          const s8b bh = *reinterpret_cast<const s8b*>(&whi[woff]);
          const s8b bl = *reinterpret_cast<const s8b*>(&wlo[woff]);
          __builtin_amdgcn_s_setprio(1);
#pragma unroll
          for (int m = 0; m < 2; ++m){
            // per-acc order: hihi -> hilo -> lohi
            acc[m][n] = __builtin_amdgcn_mfma_f32_32x32x16_bf16(ah[m], bh, acc[m][n], 0, 0, 0);
            acc[m][n] = __builtin_amdgcn_mfma_f32_32x32x16_bf16(ah[m], bl, acc[m][n], 0, 0, 0);
            acc[m][n] = __builtin_amdgcn_mfma_f32_32x32x16_bf16(al[m], bh, acc[m][n], 0, 0, 0);
          }
          __builtin_amdgcn_s_setprio(0);
        }
      }
    }
  }

  // ---- bias + relu (cout = c*128 + n*32 + li32) ----
#pragma unroll
  for (int n = 0; n < 4; ++n){
    const float bsv = bstem[c*128 + n*32 + li32];
#pragma unroll
    for (int m = 0; m < 2; ++m)
#pragma unroll
      for (int r = 0; r < 16; ++r)
        acc[m][n][r] = fmaxf(acc[m][n][r] + bsv, 0.f);
  }

  __syncthreads();                        // all A reads done; smem -> partials

  // ---- head partials: per (m, reg) pixel-row, dot over this wave's 128 couts,
  // reduce across the 32 lanes holding distinct couts (xor 1..16) ----
#pragma unroll
  for (int oc = 0; oc < 15; ++oc){
    float wv[4];
#pragma unroll
    for (int n = 0; n < 4; ++n){
      const int cc = c*128 + n*32 + li32;
      wv[n] = (oc < 3) ? wobj[oc*256 + cc] : wbox[(oc-3)*256 + cc];
    }
#pragma unroll
    for (int m = 0; m < 2; ++m){
#pragma unroll
      for (int r = 0; r < 16; ++r){
        float t = acc[m][0][r] * wv[0];
        t = fmaf(acc[m][1][r], wv[1], t);
        t = fmaf(acc[m][2][r], wv[2], t);
        t = fmaf(acc[m][3][r], wv[3], t);
        t += __shfl_xor(t, 1, 64);
        t += __shfl_xor(t, 2, 64);
        t += __shfl_xor(t, 4, 64);
        t += __shfl_xor(t, 8, 64);
        t += __shfl_xor(t, 16, 64);
        if (li32 == 0){
          const int pxcol = (r & 3) + 8*(r >> 2) + 4*hi;   // D row mapping
          const int px = (2*p + m)*32 + pxcol;
          part[(c*128 + px)*17 + oc] = t;
        }
      }
    }
  }
  __syncthreads();

  // ---- combine the two cout halves (c=0 then c=1) + bias, write out ----
  {
    const int p_idx = tid & 127, half = tid >> 7;
    const int hh = py0 + (p_idx >> 5), ww = px0 + (p_idx & 31);
    const size_t loc = (size_t)hh*W + ww;
    const int oce = half ? 15 : 8;
    for (int oc = half*8; oc < oce; ++oc){
      float s = part[(0*128 + p_idx)*17 + oc]
              + part[(1*128 + p_idx)*17 + oc];
      s += (oc < 3) ? bobj[oc] : bbox[oc-3];
      if (oc < 3) scores[(size_t)b*HW*3 + loc*3 + oc] = s;
      else        deltas[(size_t)b*HW*12 + loc*12 + (oc-3)] = s;
    }
  }
}

// ---------------- per (level,image): top-400 -> decode -> NMS -> top-50 ----------------
// radix-select -> compact -> rank-by-counting (1 barrier) -> decode -> NMS.
__global__ __launch_bounds__(1024) void k_select(
    const float* __restrict__ sc3, const float* __restrict__ sc4, const float* __restrict__ sc5,
    const float* __restrict__ dl3, const float* __restrict__ dl4, const float* __restrict__ dl5,
    float* __restrict__ out)
{
  const int lvl = blockIdx.x >> 3;
  const int b   = blockIdx.x & 7;
  int N, W; float stride; const float* sc; const float* dl;
  if (lvl==0){ N=49152; W=128; stride=8.f;  sc=sc3; dl=dl3; }
  else if (lvl==1){ N=12288; W=64; stride=16.f; sc=sc4; dl=dl4; }
  else { N=3072; W=32; stride=32.f; sc=sc5; dl=dl5; }
  sc += (size_t)b*N;
  dl += (size_t)b*(size_t)(N/3)*12;

  __shared__ unsigned hist[256];
  __shared__ unsigned s_prefix;
  __shared__ int s_need;
  __shared__ int s_cntc;
  __shared__ unsigned long long cand[1024];
  __shared__ unsigned long long srt[400];
  __shared__ float bx1[400], by1[400], bx2[400], by2[400], bar_[400];
  __shared__ unsigned long long mask[400][7];
  __shared__ int olist[50];

  const int t = threadIdx.x;

  if (t==0){ s_prefix=0u; s_need=400; }
  for (int pass=0; pass<4; ++pass){
    const int shift = 24 - 8*pass;
    if (t<256) hist[t]=0u;
    __syncthreads();
    const unsigned pref = s_prefix;
    for (int i=t; i<N; i+=1024){
      const unsigned k = okey(sc[i]);
      if (pass==0 || (k >> (shift+8)) == pref)
        atomicAdd(&hist[(k>>shift)&255u], 1u);
    }
    __syncthreads();
    if (t==0){
      int need = s_need, cum=0, bsel=0;
      for (int bb=255; bb>=0; --bb){
        const int h = (int)hist[bb];
        if (cum + h >= need){ bsel=bb; break; }
        cum += h;
      }
      s_prefix = (pref<<8) | (unsigned)bsel;
      s_need = need - cum;
    }
    __syncthreads();
  }
  const unsigned K = s_prefix;

  if (t==0) s_cntc = 0;
  cand[t] = 0ull;
  __syncthreads();
  for (int i=t; i<N; i+=1024){
    const unsigned k = okey(sc[i]);
    if (k >= K){
      const int pos = atomicAdd(&s_cntc, 1);
      if (pos < 1024)
        cand[pos] = ((unsigned long long)k<<32) | (unsigned long long)(0xFFFFFFFFu - (unsigned)i);
    }
  }
  __syncthreads();

  {
    const int cnt = (s_cntc < 1024) ? s_cntc : 1024;
    if (t < cnt){
      const unsigned long long mine = cand[t];
      int r = 0;
      for (int j = 0; j < cnt; ++j) r += (cand[j] > mine) ? 1 : 0;
      if (r < 400) srt[r] = mine;
    }
  }
  __syncthreads();

  if (t < 400){
    const unsigned long long cc = srt[t];
    const int gi = (int)(0xFFFFFFFFu - (unsigned)(cc & 0xFFFFFFFFull));
    const int loc = gi/3, a = gi - loc*3;
    const int hh = loc / W, ww = loc - hh*W;
    const float cx = (ww + 0.5f)*stride, cy = (hh + 0.5f)*stride;
    const float size = stride*8.f;
    const float sq = (a==0) ? SQH : ((a==1) ? 1.f : SQ2);
    const float hw_ = 0.5f*(size/sq);
    const float hv_ = 0.5f*(size*sq);
    const float ax1 = cx - hw_, ax2 = cx + hw_;
    const float ay1 = cy - hv_, ay2 = cy + hv_;
    const float aw = ax2 - ax1, ah = ay2 - ay1;
    const float acx = ax1 + 0.5f*aw, acy = ay1 + 0.5f*ah;
    const float* dd = dl + (size_t)loc*12 + a*4;
    const float dx = dd[0], dy = dd[1];
    const float dw = fminf(fmaxf(dd[2], -BBOX_CLAMP), BBOX_CLAMP);
    const float dh = fminf(fmaxf(dd[3], -BBOX_CLAMP), BBOX_CLAMP);
    const float pcx = acx + dx*aw;
    const float pcy = acy + dy*ah;
    const float pw = aw*expf(dw);
    const float ph = ah*expf(dh);
    const float x1 = pcx - 0.5f*pw, y1 = pcy - 0.5f*ph;
    const float x2 = pcx + 0.5f*pw, y2 = pcy + 0.5f*ph;
    bx1[t]=x1; by1[t]=y1; bx2[t]=x2; by2[t]=y2;
    bar_[t] = fmaxf(x2-x1, 0.f)*fmaxf(y2-y1, 0.f);
  }
  __syncthreads();

  for (int task=t; task<2800; task+=1024){
    const int i = task/7, w = task - (task/7)*7;
    unsigned long long m = 0ull;
    const float xi1=bx1[i], yi1=by1[i], xi2=bx2[i], yi2=by2[i], ai=bar_[i];
    const int j0 = w<<6;
    const int js = (j0 > i+1) ? j0 : (i+1);
    const int je = (j0+64 < 400) ? (j0+64) : 400;
    for (int j=js; j<je; ++j){
      const float ix1 = fmaxf(xi1, bx1[j]);
      const float iy1 = fmaxf(yi1, by1[j]);
      const float ix2 = fminf(xi2, bx2[j]);
      const float iy2 = fminf(yi2, by2[j]);
      const float inter = fmaxf(ix2-ix1, 0.f)*fmaxf(iy2-iy1, 0.f);
      const float iou = inter / fmaxf(ai + bar_[j] - inter, 1e-8f);
      if (iou > 0.6f) m |= (1ull << (j - j0));
    }
    mask[i][w] = m;
  }
  __syncthreads();

  if (t==0){
    unsigned long long keepw[7];
#pragma unroll
    for (int w=0;w<7;++w) keepw[w] = ~0ull;
    for (int i=0;i<400;++i){
      if ((keepw[i>>6] >> (i&63)) & 1ull){
#pragma unroll
        for (int w=0;w<7;++w) keepw[w] &= ~mask[i][w];
      }
    }
    int cnt=0;
    for (int i=0;i<400 && cnt<50;++i) if ( (keepw[i>>6]>>(i&63)) & 1ull) olist[cnt++]=i;
    for (int i=0;i<400 && cnt<50;++i) if (!((keepw[i>>6]>>(i&63)) & 1ull)) olist[cnt++]=i;
  }
  __syncthreads();

  if (t < 50){
    const int j = olist[t];
    float* o = out + (size_t)b*600 + (size_t)(lvl*50 + t)*4;
    o[0]=bx1[j]; o[1]=by1[j]; o[2]=bx2[j]; o[3]=by2[j];
  }
}

extern "C" void kernel_launch(void* const* d_in, const int* in_sizes, int n_in,
                              void* d_out, int out_size, void* d_ws, size_t ws_size,
                              hipStream_t stream) {
  (void)in_sizes; (void)n_in; (void)out_size; (void)ws_size;
  const float* p3     = (const float*)d_in[0];
  const float* p4     = (const float*)d_in[1];
  const float* p5     = (const float*)d_in[2];
  const float* w_stem = (const float*)d_in[3];
  const float* b_stem = (const float*)d_in[4];
  const float* w_obj  = (const float*)d_in[5];
  const float* b_obj  = (const float*)d_in[6];
  const float* w_box  = (const float*)d_in[7];
  const float* b_box  = (const float*)d_in[8];
  float* out = (float*)d_out;

  unsigned short* whi = (unsigned short*)d_ws;         // 589824 u16
  unsigned short* wlo = whi + 589824;                  // 589824 u16
  float* sc3 = (float*)(wlo + 589824);                 // 393216
  float* sc4 = sc3 + 393216;                           // 98304
  float* sc5 = sc4 + 98304;                            // 24576
  float* dl3 = sc5 + 24576;                            // 1572864
  float* dl4 = dl3 + 1572864;                          // 393216
  float* dl5 = dl4 + 393216;                           // 98304

  k_wsplit<<<dim3(2304), dim3(256), 0, stream>>>(w_stem, whi, wlo);

  k_stem_mfma<<<dim3(1344), dim3(256), 0, stream>>>(
      p3, p4, p5, whi, wlo, b_stem, w_obj, b_obj, w_box, b_box,
      sc3, dl3, sc4, dl4, sc5, dl5);

  k_select<<<dim3(24), dim3(1024), 0, stream>>>(sc3, sc4, sc5, dl3, dl4, dl5, out);
}

// Round 20
// 775.093 us; speedup vs baseline: 1.7282x; 1.7282x over previous
//
#include <hip/hip_runtime.h>
#include <math.h>
#include <stdint.h>

#define BBOX_CLAMP 4.135166556742356f
#define SQH 0.70710678118654752f
#define SQ2 1.41421356237309515f

typedef __attribute__((ext_vector_type(8))) short s8b;
typedef __attribute__((ext_vector_type(4))) float f32x4;
typedef __attribute__((ext_vector_type(4))) short s4b;

__device__ __forceinline__ unsigned okey(float f){
  unsigned u = __float_as_uint(f);
  return (u & 0x80000000u) ? ~u : (u | 0x80000000u);
}
__device__ __forceinline__ unsigned short f2bf(float f){  // RNE fp32->bf16
  unsigned u = __float_as_uint(f);
  unsigned r = (u + 0x7FFFu + ((u >> 16) & 1u)) >> 16;
  return (unsigned short)r;
}
__device__ __forceinline__ float bf2f(unsigned short h){
  return __uint_as_float(((unsigned)h) << 16);
}

// ---- one-time: split stem weights into bf16 hi/lo, MFMA-B-fragment layout ----
// whi/wlo[(((tap*8+slice)*4+g)*256 + cout)*8 + j] = split of w[cout][cin=slice*32+g*8+j][tap]
__global__ void k_wsplit(const float* __restrict__ w,
                         unsigned short* __restrict__ whi, unsigned short* __restrict__ wlo){
  const int ck = blockIdx.x;          // cin*9 + tap
  const int cout = threadIdx.x;
  const int cin = ck / 9, tap = ck - cin*9;
  const float x = w[cout*2304 + ck];
  const unsigned short h = f2bf(x);
  const unsigned short lo2 = f2bf(x - bf2f(h));
  const int slice = cin >> 5, g = (cin >> 3) & 3, j = cin & 7;
  const size_t off = ((((size_t)tap*8 + slice)*4 + g)*256 + cout)*8 + j;
  whi[off] = h; wlo[off] = lo2;
}

// ---- fused stem conv3x3 (split-bf16 MFMA) + bias + relu + obj/box heads ----
// r18 configuration — empirical optimum (775us total). 16x16x32 MFMA, wave =
// (pixel half, cout half): 64px x 128couts; A-frags read once per tap; BK=64
// staging phases (2 slices per barrier pair); setprio around MFMA clusters.
// acc[4][8]=128 AGPR + 108 arch VGPR -> 2 waves/SIMD under (256,2).
// LEDGER: min-waves>=3 always force-spills (r2/r3/r4/r14); 32x32x16 with
// f32x16 acc partially spills + dep-chains stall (r19: 88MB scratch writes,
// MfmaUtil 20%). Accumulation: phase asc -> slice asc -> tap asc ->
// (hihi,hilo,lohi) per acc — bit-identical chain across all passing rounds.
__global__ __launch_bounds__(256, 2) void k_stem_mfma(
    const float* __restrict__ p3f, const float* __restrict__ p4f, const float* __restrict__ p5f,
    const unsigned short* __restrict__ whi, const unsigned short* __restrict__ wlo,
    const float* __restrict__ bstem,
    const float* __restrict__ wobj, const float* __restrict__ bobj,
    const float* __restrict__ wbox, const float* __restrict__ bbox,
    float* __restrict__ sc3, float* __restrict__ dl3,
    float* __restrict__ sc4, float* __restrict__ dl4,
    float* __restrict__ sc5, float* __restrict__ dl5)
{
  // A tile: [sl2][plane][204][40] u16 = 4*8160 u16 = 65280 B.
  // head partials (4 waves x 64 px x 17 f32 = 17408 B) overlay after compute.
  __shared__ __align__(16) unsigned char smem[65280];
  unsigned short* Abuf = reinterpret_cast<unsigned short*>(smem);
  float* part = reinterpret_cast<float*>(smem);

  const int tid = threadIdx.x;
  const int l = tid & 63, w = tid >> 6;
  const int li = l & 15, g = l >> 4;
  const int p = w >> 1, c = w & 1;    // pixel half (rows 2p,2p+1), cout half

  // ---- level decode ----
  int id = blockIdx.x;
  const float* feat; float* scores; float* deltas; int H, W, bx, by, b;
  if (id < 1024){ feat=p3f; scores=sc3; deltas=dl3; H=128; W=128;
      bx = id & 3; by = (id >> 2) & 31; b = id >> 7; }
  else if (id < 1280){ id -= 1024; feat=p4f; scores=sc4; deltas=dl4; H=64; W=64;
      bx = id & 1; by = (id >> 1) & 15; b = id >> 5; }
  else { id -= 1280; feat=p5f; scores=sc5; deltas=dl5; H=32; W=32;
      bx = 0; by = id & 7; b = id >> 3; }
  const int px0 = bx*32, py0 = by*4;
  const size_t HW = (size_t)H*W;
  const float* fb = feat + (size_t)b*256*HW;

  // ---- staging map: thread = halo pixel, iter = cin ----
  const int gr = tid / 34, gc = tid - gr*34;
  const int row = py0 + gr - 1, col = px0 + gc - 1;
  const bool inb = (tid < 204) && row >= 0 && row < H && col >= 0 && col < W;
  const bool lact = (tid < 204);
  const float* gA = fb + ((size_t)(inb ? row : 0)*W + (inb ? col : 0));

  f32x4 acc[4][8];
#pragma unroll
  for (int m=0;m<4;++m)
#pragma unroll
    for (int cg=0;cg<8;++cg) acc[m][cg] = (f32x4){0.f,0.f,0.f,0.f};

  for (int ph = 0; ph < 4; ++ph){
    __syncthreads();                      // prior phase's A reads done
    // ---- stage 2 slices (64 cins) this phase ----
#pragma unroll
    for (int sl2 = 0; sl2 < 2; ++sl2){
      const float* gs = gA + (size_t)(ph*2 + sl2)*32*HW;
      unsigned short* Ab = Abuf + sl2*16320;
#pragma unroll
      for (int ch = 0; ch < 8; ++ch){
        float x0=0.f, x1=0.f, x2=0.f, x3=0.f;
        if (inb){
          x0 = gs[(size_t)(ch*4+0)*HW];
          x1 = gs[(size_t)(ch*4+1)*HW];
          x2 = gs[(size_t)(ch*4+2)*HW];
          x3 = gs[(size_t)(ch*4+3)*HW];
        }
        if (lact){
          const unsigned short h0=f2bf(x0), h1=f2bf(x1), h2=f2bf(x2), h3=f2bf(x3);
          s4b hv; hv[0]=(short)h0; hv[1]=(short)h1; hv[2]=(short)h2; hv[3]=(short)h3;
          s4b lv; lv[0]=(short)f2bf(x0-bf2f(h0)); lv[1]=(short)f2bf(x1-bf2f(h1));
                  lv[2]=(short)f2bf(x2-bf2f(h2)); lv[3]=(short)f2bf(x3-bf2f(h3));
          *reinterpret_cast<s4b*>(&Ab[tid*40 + ch*4]) = hv;
          *reinterpret_cast<s4b*>(&Ab[8160 + tid*40 + ch*4]) = lv;
        }
      }
    }
    __syncthreads();

    // ---- compute both slices (slice asc; per-acc chain bit-identical) ----
#pragma unroll
    for (int sl2 = 0; sl2 < 2; ++sl2){
      const int slice = ph*2 + sl2;
      const unsigned short* Ab = Abuf + sl2*16320;
      for (int tap = 0; tap < 9; ++tap){
        const int dr = tap/3 - 1, dc = tap - (tap/3)*3 - 1;
        // A fragments: read ONCE per tap (8 b128), reuse across chunks
        s8b ah[4], al[4];
#pragma unroll
        for (int m = 0; m < 4; ++m){
          const int rm = 2*p + (m >> 1), cm = m & 1;
          const int aoff = ((rm+dr+1)*34 + cm*16 + li + dc + 1)*40 + g*8;
          ah[m] = *reinterpret_cast<const s8b*>(&Ab[aoff]);
          al[m] = *reinterpret_cast<const s8b*>(&Ab[8160 + aoff]);
        }
        // two cout chunks of 4 cg each
#pragma unroll
        for (int chunk = 0; chunk < 2; ++chunk){
          s8b bh[4], bl[4];
#pragma unroll
          for (int cg4 = 0; cg4 < 4; ++cg4){
            const int cout = c*128 + (chunk*4 + cg4)*16 + li;
            const int woff = ((((tap*8 + slice)*4 + g)*256) + cout)*8;
            bh[cg4] = *reinterpret_cast<const s8b*>(&whi[woff]);
            bl[cg4] = *reinterpret_cast<const s8b*>(&wlo[woff]);
          }
          __builtin_amdgcn_s_setprio(1);
#pragma unroll
          for (int m = 0; m < 4; ++m){
            // per-acc order: hihi -> hilo -> lohi (bit-identical chain)
#pragma unroll
            for (int cg4 = 0; cg4 < 4; ++cg4)
              acc[m][chunk*4+cg4] = __builtin_amdgcn_mfma_f32_16x16x32_bf16(ah[m], bh[cg4], acc[m][chunk*4+cg4], 0, 0, 0);
#pragma unroll
            for (int cg4 = 0; cg4 < 4; ++cg4)
              acc[m][chunk*4+cg4] = __builtin_amdgcn_mfma_f32_16x16x32_bf16(ah[m], bl[cg4], acc[m][chunk*4+cg4], 0, 0, 0);
#pragma unroll
            for (int cg4 = 0; cg4 < 4; ++cg4)
              acc[m][chunk*4+cg4] = __builtin_amdgcn_mfma_f32_16x16x32_bf16(al[m], bh[cg4], acc[m][chunk*4+cg4], 0, 0, 0);
          }
          __builtin_amdgcn_s_setprio(0);
        }
      }
    }
  }

  // ---- bias + relu (cout = c*128 + cg*16 + li) ----
#pragma unroll
  for (int cg = 0; cg < 8; ++cg){
    const float bsv = bstem[c*128 + cg*16 + li];
#pragma unroll
    for (int m = 0; m < 4; ++m)
#pragma unroll
      for (int r = 0; r < 4; ++r)
        acc[m][cg][r] = fmaxf(acc[m][cg][r] + bsv, 0.f);
  }

  __syncthreads();                        // all A reads done; smem -> partials

  // ---- head partials: wave-local 128-cout dot, 16-lane shuffle tree ----
#pragma unroll
  for (int oc = 0; oc < 15; ++oc){
    float wv[8];
#pragma unroll
    for (int cg = 0; cg < 8; ++cg){
      const int cc = c*128 + cg*16 + li;
      wv[cg] = (oc < 3) ? wobj[oc*256 + cc] : wbox[(oc-3)*256 + cc];
    }
#pragma unroll
    for (int m = 0; m < 4; ++m){
#pragma unroll
      for (int r = 0; r < 4; ++r){
        float t = acc[m][0][r] * wv[0];
#pragma unroll
        for (int cg = 1; cg < 8; ++cg) t = fmaf(acc[m][cg][r], wv[cg], t);
        t += __shfl_xor(t, 1, 64);
        t += __shfl_xor(t, 2, 64);
        t += __shfl_xor(t, 4, 64);
        t += __shfl_xor(t, 8, 64);
        if (li == 0)
          part[(w*64 + m*16 + g*4 + r)*17 + oc] = t;
      }
    }
  }
  __syncthreads();

  // ---- combine the two cout halves + bias, write scores/deltas ----
  {
    const int p_idx = tid & 127, half = tid >> 7;
    const int mg = p_idx >> 4, i16 = p_idx & 15;
    const int rm = mg >> 1, cm = mg & 1;
    const int pp = mg >> 2, ml = mg & 3;
    const int hh = py0 + rm, ww = px0 + cm*16 + i16;
    const size_t loc = (size_t)hh*W + ww;
    const int oce = half ? 15 : 8;
    for (int oc = half*8; oc < oce; ++oc){
      float s = part[((2*pp)*64 + ml*16 + i16)*17 + oc]
              + part[((2*pp+1)*64 + ml*16 + i16)*17 + oc];
      s += (oc < 3) ? bobj[oc] : bbox[oc-3];
      if (oc < 3) scores[(size_t)b*HW*3 + loc*3 + oc] = s;
      else        deltas[(size_t)b*HW*12 + loc*12 + (oc-3)] = s;
    }
  }
}

// ---------------- per (level,image): top-400 -> decode -> NMS -> top-50 ----------------
// radix-select -> compact -> rank-by-counting (1 barrier) -> decode -> NMS.
__global__ __launch_bounds__(1024) void k_select(
    const float* __restrict__ sc3, const float* __restrict__ sc4, const float* __restrict__ sc5,
    const float* __restrict__ dl3, const float* __restrict__ dl4, const float* __restrict__ dl5,
    float* __restrict__ out)
{
  const int lvl = blockIdx.x >> 3;
  const int b   = blockIdx.x & 7;
  int N, W; float stride; const float* sc; const float* dl;
  if (lvl==0){ N=49152; W=128; stride=8.f;  sc=sc3; dl=dl3; }
  else if (lvl==1){ N=12288; W=64; stride=16.f; sc=sc4; dl=dl4; }
  else { N=3072; W=32; stride=32.f; sc=sc5; dl=dl5; }
  sc += (size_t)b*N;
  dl += (size_t)b*(size_t)(N/3)*12;

  __shared__ unsigned hist[256];
  __shared__ unsigned s_prefix;
  __shared__ int s_need;
  __shared__ int s_cntc;
  __shared__ unsigned long long cand[1024];
  __shared__ unsigned long long srt[400];
  __shared__ float bx1[400], by1[400], bx2[400], by2[400], bar_[400];
  __shared__ unsigned long long mask[400][7];
  __shared__ int olist[50];

  const int t = threadIdx.x;

  if (t==0){ s_prefix=0u; s_need=400; }
  for (int pass=0; pass<4; ++pass){
    const int shift = 24 - 8*pass;
    if (t<256) hist[t]=0u;
    __syncthreads();
    const unsigned pref = s_prefix;
    for (int i=t; i<N; i+=1024){
      const unsigned k = okey(sc[i]);
      if (pass==0 || (k >> (shift+8)) == pref)
        atomicAdd(&hist[(k>>shift)&255u], 1u);
    }
    __syncthreads();
    if (t==0){
      int need = s_need, cum=0, bsel=0;
      for (int bb=255; bb>=0; --bb){
        const int h = (int)hist[bb];
        if (cum + h >= need){ bsel=bb; break; }
        cum += h;
      }
      s_prefix = (pref<<8) | (unsigned)bsel;
      s_need = need - cum;
    }
    __syncthreads();
  }
  const unsigned K = s_prefix;

  if (t==0) s_cntc = 0;
  cand[t] = 0ull;
  __syncthreads();
  for (int i=t; i<N; i+=1024){
    const unsigned k = okey(sc[i]);
    if (k >= K){
      const int pos = atomicAdd(&s_cntc, 1);
      if (pos < 1024)
        cand[pos] = ((unsigned long long)k<<32) | (unsigned long long)(0xFFFFFFFFu - (unsigned)i);
    }
  }
  __syncthreads();

  {
    const int cnt = (s_cntc < 1024) ? s_cntc : 1024;
    if (t < cnt){
      const unsigned long long mine = cand[t];
      int r = 0;
      for (int j = 0; j < cnt; ++j) r += (cand[j] > mine) ? 1 : 0;
      if (r < 400) srt[r] = mine;
    }
  }
  __syncthreads();

  if (t < 400){
    const unsigned long long cc = srt[t];
    const int gi = (int)(0xFFFFFFFFu - (unsigned)(cc & 0xFFFFFFFFull));
    const int loc = gi/3, a = gi - loc*3;
    const int hh = loc / W, ww = loc - hh*W;
    const float cx = (ww + 0.5f)*stride, cy = (hh + 0.5f)*stride;
    const float size = stride*8.f;
    const float sq = (a==0) ? SQH : ((a==1) ? 1.f : SQ2);
    const float hw_ = 0.5f*(size/sq);
    const float hv_ = 0.5f*(size*sq);
    const float ax1 = cx - hw_, ax2 = cx + hw_;
    const float ay1 = cy - hv_, ay2 = cy + hv_;
    const float aw = ax2 - ax1, ah = ay2 - ay1;
    const float acx = ax1 + 0.5f*aw, acy = ay1 + 0.5f*ah;
    const float* dd = dl + (size_t)loc*12 + a*4;
    const float dx = dd[0], dy = dd[1];
    const float dw = fminf(fmaxf(dd[2], -BBOX_CLAMP), BBOX_CLAMP);
    const float dh = fminf(fmaxf(dd[3], -BBOX_CLAMP), BBOX_CLAMP);
    const float pcx = acx + dx*aw;
    const float pcy = acy + dy*ah;
    const float pw = aw*expf(dw);
    const float ph = ah*expf(dh);
    const float x1 = pcx - 0.5f*pw, y1 = pcy - 0.5f*ph;
    const float x2 = pcx + 0.5f*pw, y2 = pcy + 0.5f*ph;
    bx1[t]=x1; by1[t]=y1; bx2[t]=x2; by2[t]=y2;
    bar_[t] = fmaxf(x2-x1, 0.f)*fmaxf(y2-y1, 0.f);
  }
  __syncthreads();

  for (int task=t; task<2800; task+=1024){
    const int i = task/7, w = task - (task/7)*7;
    unsigned long long m = 0ull;
    const float xi1=bx1[i], yi1=by1[i], xi2=bx2[i], yi2=by2[i], ai=bar_[i];
    const int j0 = w<<6;
    const int js = (j0 > i+1) ? j0 : (i+1);
    const int je = (j0+64 < 400) ? (j0+64) : 400;
    for (int j=js; j<je; ++j){
      const float ix1 = fmaxf(xi1, bx1[j]);
      const float iy1 = fmaxf(yi1, by1[j]);
      const float ix2 = fminf(xi2, bx2[j]);
      const float iy2 = fminf(yi2, by2[j]);
      const float inter = fmaxf(ix2-ix1, 0.f)*fmaxf(iy2-iy1, 0.f);
      const float iou = inter / fmaxf(ai + bar_[j] - inter, 1e-8f);
      if (iou > 0.6f) m |= (1ull << (j - j0));
    }
    mask[i][w] = m;
  }
  __syncthreads();

  if (t==0){
    unsigned long long keepw[7];
#pragma unroll
    for (int w=0;w<7;++w) keepw[w] = ~0ull;
    for (int i=0;i<400;++i){
      if ((keepw[i>>6] >> (i&63)) & 1ull){
#pragma unroll
        for (int w=0;w<7;++w) keepw[w] &= ~mask[i][w];
      }
    }
    int cnt=0;
    for (int i=0;i<400 && cnt<50;++i) if ( (keepw[i>>6]>>(i&63)) & 1ull) olist[cnt++]=i;
    for (int i=0;i<400 && cnt<50;++i) if (!((keepw[i>>6]>>(i&63)) & 1ull)) olist[cnt++]=i;
  }
  __syncthreads();

  if (t < 50){
    const int j = olist[t];
    float* o = out + (size_t)b*600 + (size_t)(lvl*50 + t)*4;
    o[0]=bx1[j]; o[1]=by1[j]; o[2]=bx2[j]; o[3]=by2[j];
  }
}

extern "C" void kernel_launch(void* const* d_in, const int* in_sizes, int n_in,
                              void* d_out, int out_size, void* d_ws, size_t ws_size,
                              hipStream_t stream) {
  (void)in_sizes; (void)n_in; (void)out_size; (void)ws_size;
  const float* p3     = (const float*)d_in[0];
  const float* p4     = (const float*)d_in[1];
  const float* p5     = (const float*)d_in[2];
  const float* w_stem = (const float*)d_in[3];
  const float* b_stem = (const float*)d_in[4];
  const float* w_obj  = (const float*)d_in[5];
  const float* b_obj  = (const float*)d_in[6];
  const float* w_box  = (const float*)d_in[7];
  const float* b_box  = (const float*)d_in[8];
  float* out = (float*)d_out;

  unsigned short* whi = (unsigned short*)d_ws;         // 589824 u16
  unsigned short* wlo = whi + 589824;                  // 589824 u16
  float* sc3 = (float*)(wlo + 589824);                 // 393216
  float* sc4 = sc3 + 393216;                           // 98304
  float* sc5 = sc4 + 98304;                            // 24576
  float* dl3 = sc5 + 24576;                            // 1572864
  float* dl4 = dl3 + 1572864;                          // 393216
  float* dl5 = dl4 + 393216;                           // 98304

  k_wsplit<<<dim3(2304), dim3(256), 0, stream>>>(w_stem, whi, wlo);

  k_stem_mfma<<<dim3(1344), dim3(256), 0, stream>>>(
      p3, p4, p5, whi, wlo, b_stem, w_obj, b_obj, w_box, b_box,
      sc3, dl3, sc4, dl4, sc5, dl5);

  k_select<<<dim3(24), dim3(1024), 0, stream>>>(sc3, sc4, sc5, dl3, dl4, dl5, out);
}